// Round 14
// baseline (1197.382 us; speedup 1.0000x reference)
//
#include <hip/hip_runtime.h>
#include <math.h>

// Problem constants (reference: B,P,D,N,K = 8,784,1536,20000,9)
#define B_    8
#define P_    784
#define M_    6272      // B*P
#define D_    1536
#define N_    20000
#define NC_   8         // candidate patches per image (fp8 ranking noise -> wider net)

// 256x256 fp8 GEMM geometry (BK = 128 fp8 = one MFMA K-step)
#define MPAD  6400      // 25*256
#define NPAD2 20224     // 79*256
#define MT2   25
#define NT2   79
#define KT2   12        // 1536/128 K-tiles

#define NBLK  1250      // cand-dist blocks of 16 rows (1250*16 = 20000 exactly)

using i32x8  = __attribute__((ext_vector_type(8))) int;
using f32x4v = __attribute__((ext_vector_type(4))) float;

#define GLD_LDS16(src, dst)                                            \
  __builtin_amdgcn_global_load_lds(                                    \
      (__attribute__((address_space(1))) const void*)(src),            \
      (__attribute__((address_space(3))) void*)(dst), 16, 0, 0)

// order-preserving float<->uint for atomicMin (all finite values)
__device__ __forceinline__ unsigned fenc(float f) {
  unsigned u = __float_as_uint(f);
  return (u >> 31) ? ~u : (u | 0x80000000u);
}
__device__ __forceinline__ float fdec(unsigned k) {
  return (k >> 31) ? __uint_as_float(k & 0x7FFFFFFFu) : __uint_as_float(~k);
}

// Branchless sorted-ascending top-9 insert, compile-time indices ONLY (rule #20).
__device__ __forceinline__ void ins9(float* t, float v) {
  float tim1 = t[0];
  t[0] = fminf(t[0], v);
#pragma unroll
  for (int i = 1; i < 9; ++i) {
    float cur = t[i];
    t[i] = fminf(cur, fmaxf(tim1, v));
    tim1 = cur;
  }
}

// ---------------- K1: fused fp32 -> fp8 (HW cvt) + row sum-of-squares + min-buffer init ------
__device__ __forceinline__ void convert_one(const float* __restrict__ src,
                                            unsigned char* __restrict__ dst,
                                            float* __restrict__ sq,
                                            int row, int realrows) {
  const int t = threadIdx.x;
  if (row >= realrows) {
    unsigned* w = (unsigned*)(dst + (size_t)row * D_);
    for (int i = t; i < D_ / 4; i += 256) w[i] = 0u;   // fp8 zero
    if (t == 0) sq[row] = 1e30f;
    return;
  }
  const float4* r4 = (const float4*)(src + (size_t)row * D_);
  unsigned* w = (unsigned*)(dst + (size_t)row * D_);
  float s = 0.f;
  for (int i = t; i < D_ / 4; i += 256) {
    float4 v = r4[i];
    s += v.x * v.x + v.y * v.y + v.z * v.z + v.w * v.w;
    int pk = __builtin_amdgcn_cvt_pk_fp8_f32(v.x, v.y, 0, false);   // low 16 bits
    pk     = __builtin_amdgcn_cvt_pk_fp8_f32(v.z, v.w, pk, true);   // high 16 bits
    w[i] = (unsigned)pk;
  }
#pragma unroll
  for (int m = 32; m >= 1; m >>= 1) s += __shfl_xor(s, m);
  __shared__ float ws4[4];
  if ((t & 63) == 0) ws4[t >> 6] = s;
  __syncthreads();
  if (t == 0) sq[row] = ws4[0] + ws4[1] + ws4[2] + ws4[3];
}

__global__ void convert_all(const float* __restrict__ x, const float* __restrict__ mem,
                            unsigned char* __restrict__ xq, unsigned char* __restrict__ mq,
                            float* __restrict__ x2, float* __restrict__ m2,
                            unsigned* __restrict__ closest_enc) {
  const int blk = blockIdx.x;
  if (blk < MPAD / 256)   // fold the min-buffer init (per-call reinit; replay-safe)
    closest_enc[blk * 256 + threadIdx.x] = 0xFFFFFFFFu;
  if (blk < NPAD2) convert_one(mem, mq, m2, blk, N_);
  else convert_one(x, xq, x2, blk - NPAD2, M_);
}

// ---------------- K2: 256x256 fp8 MX-MFMA GEMM, B-in-registers, 1 barrier/K-tile -------------
// A through LDS (dbuf 2x32KB, T2 swizzle, gld_lds); B fragments loaded DIRECTLY from global
// into registers (32B/lane, 128B-line covered, L2-hot: each B row reused by 25 mT blocks).
// Removes B staging -> single barrier + vmcnt(0) per K-tile (A-dbuf hazard only), LDS reads
// 24->16/wave/kt, LDS writes halved. bf double-buffer via compile-time parity (2-kt unroll).
__global__ __launch_bounds__(512, 2) void gemm_min8(
    const unsigned char* __restrict__ xq, const unsigned char* __restrict__ mq,
    const float* __restrict__ m2, unsigned* __restrict__ closest_enc) {
  __shared__ __attribute__((aligned(16))) char ldsA[65536];
  __shared__ float ldsMin[4][256];

  // --- block swizzle: bijective XCD chunking + 5-mTile supertiles ---
  const int NWG = MT2 * NT2;              // 1975
  const int bid = blockIdx.x;
  const int q = NWG >> 3, r = NWG & 7;    // 246, 7
  const int xcd = bid & 7, loc = bid >> 3;
  const int wg = (xcd < r ? xcd * (q + 1) : r * (q + 1) + (xcd - r) * q) + loc;
  const int s = wg / (5 * NT2);
  const int r2 = wg - s * (5 * NT2);
  const int mT = s * 5 + (r2 % 5);
  const int nT = r2 / 5;

  const int tid = threadIdx.x;
  const int lane = tid & 63, wid = tid >> 6;
  const int wm = wid >> 2, wn = wid & 3;      // 2 x 4 wave grid
  const int g = lane >> 4, r16 = lane & 15;
  const int mBase = mT * 256, nBase = nT * 256;

  const int stA = mBase + wid * 8 + (lane >> 3);
  const int cswz16 = ((lane & 7) ^ ((lane >> 3) & 7)) * 16;  // inverse-swizzled byte col

  // LDS reader: row byte-offset row*128; k-chunk (g*32) swizzled by ((r16&7)<<4)
  const int csl = (g * 32) ^ ((r16 & 7) << 4);
  const int csh = csl ^ 16;                     // (g*32+16)^swz (bit4 of g*32 == 0)
  const int rdA = wm * 16384 + r16 * 128;       // + mf*2048 (+ buf*32768)

  // B global base (per-lane): row nBase + wn*64 + nf*16 + r16, col kt*128 + g*32 (no swizzle)
  const unsigned char* bbase = mq + (size_t)(nBase + wn * 64 + r16) * 1536 + g * 32;

#define STAGEA(bufb, h, ktv) do {                                           \
    char* dst_ = ldsA + (bufb) * 32768 + (h) * 16384 + wid * 1024;          \
    const unsigned char* s_ =                                               \
        xq + (size_t)((stA) + (h) * 128) * 1536 + (ktv) * 128 + cswz16;     \
    GLD_LDS16(s_, dst_);                                                    \
    GLD_LDS16(s_ + 64 * 1536, dst_ + 8192);                                 \
  } while (0)

#define LOADB(dst, ktv) do {                                                \
    _Pragma("unroll")                                                       \
    for (int nf_ = 0; nf_ < 4; ++nf_) {                                     \
      const unsigned char* bp_ = bbase + (size_t)nf_ * 16 * 1536 + (ktv) * 128; \
      int4 lo_ = *(const int4*)bp_;                                         \
      int4 hi_ = *(const int4*)(bp_ + 16);                                  \
      dst[nf_] = i32x8{lo_.x, lo_.y, lo_.z, lo_.w, hi_.x, hi_.y, hi_.z, hi_.w}; \
    }                                                                       \
  } while (0)

#define LDFRAG(base, off) ({                                                \
    int4 lo_ = *(const int4*)((base) + (off) + csl);                        \
    int4 hi_ = *(const int4*)((base) + (off) + csh);                        \
    i32x8{lo_.x, lo_.y, lo_.z, lo_.w, hi_.x, hi_.y, hi_.z, hi_.w}; })

#define MFMA8(a, b, c) __builtin_amdgcn_mfma_scale_f32_16x16x128_f8f6f4(    \
    (a), (b), (c), 0, 0, 0, 0x7F7F7F7F, 0, 0x7F7F7F7F)

  f32x4v acc[8][4];
#pragma unroll
  for (int i = 0; i < 8; ++i)
#pragma unroll
    for (int j = 0; j < 4; ++j) acc[i][j] = f32x4v{0.f, 0.f, 0.f, 0.f};

  i32x8 bf0[4], bf1[4];

  // ---- prologue: A(0) -> buf0, B(0) -> bf0 ----
  STAGEA(0, 0, 0);
  STAGEA(0, 1, 0);
  LOADB(bf0, 0);
  asm volatile("s_waitcnt vmcnt(0)");
  __builtin_amdgcn_s_barrier();
  __builtin_amdgcn_sched_barrier(0);

  // ---- K-loop: one barrier per K-tile; A-dbuf in LDS, B reg-double-buffered by parity ----
#define KTBODY(ktv, BFC, BFN) do {                                          \
    const char* Ab_ = ldsA + ((ktv) & 1) * 32768;                           \
    i32x8 af_[4];                                                           \
    _Pragma("unroll")                                                       \
    for (int mf_ = 0; mf_ < 4; ++mf_) af_[mf_] = LDFRAG(Ab_, rdA + mf_ * 2048); \
    if ((ktv) + 1 < KT2) {                                                  \
      STAGEA(((ktv) & 1) ^ 1, 0, (ktv) + 1);                                \
      STAGEA(((ktv) & 1) ^ 1, 1, (ktv) + 1);                                \
      LOADB(BFN, (ktv) + 1);                                                \
    }                                                                       \
    asm volatile("s_waitcnt lgkmcnt(0)");                                   \
    __builtin_amdgcn_s_setprio(1);                                          \
    _Pragma("unroll")                                                       \
    for (int mf_ = 0; mf_ < 4; ++mf_)                                       \
      _Pragma("unroll")                                                     \
      for (int nf_ = 0; nf_ < 4; ++nf_)                                     \
        acc[mf_][nf_] = MFMA8(af_[mf_], BFC[nf_], acc[mf_][nf_]);           \
    __builtin_amdgcn_s_setprio(0);                                          \
    _Pragma("unroll")                                                       \
    for (int mf_ = 0; mf_ < 4; ++mf_) af_[mf_] = LDFRAG(Ab_, rdA + (mf_ + 4) * 2048); \
    asm volatile("s_waitcnt lgkmcnt(0)");                                   \
    __builtin_amdgcn_s_setprio(1);                                          \
    _Pragma("unroll")                                                       \
    for (int mf_ = 0; mf_ < 4; ++mf_)                                       \
      _Pragma("unroll")                                                     \
      for (int nf_ = 0; nf_ < 4; ++nf_)                                     \
        acc[mf_ + 4][nf_] = MFMA8(af_[mf_], BFC[nf_], acc[mf_ + 4][nf_]);   \
    __builtin_amdgcn_s_setprio(0);                                          \
    asm volatile("s_waitcnt vmcnt(0)");                                     \
    __builtin_amdgcn_s_barrier();                                           \
    __builtin_amdgcn_sched_barrier(0);                                      \
  } while (0)

#pragma unroll 1
  for (int ktp = 0; ktp < KT2 / 2; ++ktp) {
    KTBODY(2 * ktp,     bf0, bf1);
    KTBODY(2 * ktp + 1, bf1, bf0);
  }
#undef KTBODY
#undef STAGEA
#undef LOADB
#undef LDFRAG
#undef MFMA8

  // ---- epilogue: per-row min over this tile's 256 cols -> global atomicMin ----
  // C/D layout: col = nBase + wn*64 + nf*16 + (lane&15), row = wm*128 + mf*16 + (lane>>4)*4 + i
  float m2v[4];
#pragma unroll
  for (int nf = 0; nf < 4; ++nf) m2v[nf] = m2[nBase + wn * 64 + nf * 16 + r16];
#pragma unroll
  for (int mf = 0; mf < 8; ++mf) {
    float mn[4];
#pragma unroll
    for (int i = 0; i < 4; ++i) {
      float v = m2v[0] - 2.f * acc[mf][0][i];
      v = fminf(v, m2v[1] - 2.f * acc[mf][1][i]);
      v = fminf(v, m2v[2] - 2.f * acc[mf][2][i]);
      v = fminf(v, m2v[3] - 2.f * acc[mf][3][i]);
      mn[i] = v;
    }
#pragma unroll
    for (int msk = 1; msk < 16; msk <<= 1)
#pragma unroll
      for (int i = 0; i < 4; ++i) mn[i] = fminf(mn[i], __shfl_xor(mn[i], msk));
    if (r16 == 0)
#pragma unroll
      for (int i = 0; i < 4; ++i)
        ldsMin[wn][wm * 128 + mf * 16 + g * 4 + i] = mn[i];
  }
  __syncthreads();
  if (tid < 256) {
    float v = fminf(fminf(ldsMin[0][tid], ldsMin[1][tid]),
                    fminf(ldsMin[2][tid], ldsMin[3][tid]));
    atomicMin(&closest_enc[mBase + tid], fenc(v));
  }
}

// ---------------- K3: per image, closest = x2 + decoded min; wave-parallel top-NC ----------------
__global__ void topcand_kernel(const unsigned* __restrict__ closest_enc,
                               const float* __restrict__ x2,
                               int* __restrict__ cand) {
  const int b = blockIdx.x;
  const int t = threadIdx.x;
  __shared__ float cls[P_];
  for (int p = t; p < P_; p += 256) {
    const int row = b * P_ + p;
    cls[p] = x2[row] + fdec(closest_enc[row]);
  }
  __syncthreads();
  __shared__ float wv[4];
  __shared__ int wi_[4];
  __shared__ int picked[NC_];
  for (int r = 0; r < NC_; ++r) {
    float mv = -3e38f; int mi = 1 << 30;
    for (int p = t; p < P_; p += 256) {
      bool skip = false;
      for (int c = 0; c < r; ++c) skip |= (picked[c] == p);
      float v = cls[p];
      if (!skip && (v > mv || (v == mv && p < mi))) { mv = v; mi = p; }
    }
#pragma unroll
    for (int m = 32; m >= 1; m >>= 1) {
      float ov = __shfl_xor(mv, m); int oi = __shfl_xor(mi, m);
      if (ov > mv || (ov == mv && oi < mi)) { mv = ov; mi = oi; }
    }
    if ((t & 63) == 0) { wv[t >> 6] = mv; wi_[t >> 6] = mi; }
    __syncthreads();
    if (t == 0) {
      float bv = wv[0]; int bi = wi_[0];
      for (int w = 1; w < 4; ++w)
        if (wv[w] > bv || (wv[w] == bv && wi_[w] < bi)) { bv = wv[w]; bi = wi_[w]; }
      picked[r] = bi;
      cand[b * NC_ + r] = bi;
    }
    __syncthreads();
  }
}

// ---------------- K4: exact fp32 distances, ONE pass over memory + per-block top-9 ----------------
// 1250 blocks x 4 waves; each wave owns 4 rows (m4[4][6] = 96 VGPR, spill-free).
__global__ __launch_bounds__(256) void cand_dist9(
    const float* __restrict__ x, const float* __restrict__ mem,
    const float* __restrict__ x2, const float* __restrict__ m2,
    const int* __restrict__ cand, float* __restrict__ ctop) {
  const int wid = threadIdx.x >> 6, lane = threadIdx.x & 63;
  const int blk = blockIdx.x;
  __shared__ float ldsD[B_ * NC_][20];  // [pair][row-in-block], padded (2-way bank alias = free)

  const int rbase = blk * 16 + wid * 4;
  float4 m4[4][6];
  float m2r[4];
#pragma unroll
  for (int k = 0; k < 4; ++k) {
    const float4* mrow = (const float4*)(mem + (size_t)(rbase + k) * D_);
#pragma unroll
    for (int j = 0; j < 6; ++j) m4[k][j] = mrow[j * 64 + lane];
    m2r[k] = m2[rbase + k];
  }
#pragma unroll 2
  for (int bc = 0; bc < B_ * NC_; ++bc) {
    const int b = bc / NC_;
    const int p = cand[bc];
    const float4* xp = (const float4*)(x + ((size_t)b * P_ + p) * D_);
    float s0 = 0.f, s1 = 0.f, s2 = 0.f, s3 = 0.f;
#pragma unroll
    for (int j = 0; j < 6; ++j) {
      float4 a = xp[j * 64 + lane];
      s0 += a.x * m4[0][j].x + a.y * m4[0][j].y + a.z * m4[0][j].z + a.w * m4[0][j].w;
      s1 += a.x * m4[1][j].x + a.y * m4[1][j].y + a.z * m4[1][j].z + a.w * m4[1][j].w;
      s2 += a.x * m4[2][j].x + a.y * m4[2][j].y + a.z * m4[2][j].z + a.w * m4[2][j].w;
      s3 += a.x * m4[3][j].x + a.y * m4[3][j].y + a.z * m4[3][j].z + a.w * m4[3][j].w;
    }
#pragma unroll
    for (int msk = 32; msk >= 1; msk >>= 1) {
      s0 += __shfl_xor(s0, msk); s1 += __shfl_xor(s1, msk);
      s2 += __shfl_xor(s2, msk); s3 += __shfl_xor(s3, msk);
    }
    if (lane == 0) {
      const float xx = x2[b * P_ + p];
      ldsD[bc][wid * 4 + 0] = xx + m2r[0] - 2.f * s0;
      ldsD[bc][wid * 4 + 1] = xx + m2r[1] - 2.f * s1;
      ldsD[bc][wid * 4 + 2] = xx + m2r[2] - 2.f * s2;
      ldsD[bc][wid * 4 + 3] = xx + m2r[3] - 2.f * s3;
    }
  }
  __syncthreads();
  if (lane < 16) {
    const int bc = wid * 16 + lane;
    float t[9];
#pragma unroll
    for (int i = 0; i < 9; ++i) t[i] = 3e38f;
#pragma unroll
    for (int i = 0; i < 16; ++i) ins9(t, ldsD[bc][i]);
    float* o = ctop + ((size_t)bc * NBLK + blk) * 9;
#pragma unroll
    for (int i = 0; i < 9; ++i) o[i] = t[i];
  }
}

// ---------------- K5: merge per-block top-9 partials -> exact top-9 per (image,cand) ----------
__global__ void merge_top9(const float* __restrict__ ctop, float* __restrict__ top9) {
  const int bc = blockIdx.x;  // 0..63
  const float* d = ctop + (size_t)bc * (NBLK * 9);
  float t[9];
#pragma unroll
  for (int i = 0; i < 9; ++i) t[i] = 3e38f;
  for (int n = threadIdx.x; n < NBLK * 9; n += 256) ins9(t, d[n]);
  __shared__ float l9[256 * 9];
  __shared__ float l9b[32 * 9];
#pragma unroll
  for (int i = 0; i < 9; ++i) l9[threadIdx.x * 9 + i] = t[i];
  __syncthreads();
  if (threadIdx.x < 32) {
    float u[9];
#pragma unroll
    for (int i = 0; i < 9; ++i) u[i] = 3e38f;
    for (int s = 0; s < 8; ++s)
#pragma unroll
      for (int i = 0; i < 9; ++i) ins9(u, l9[(threadIdx.x * 8 + s) * 9 + i]);
#pragma unroll
    for (int i = 0; i < 9; ++i) l9b[threadIdx.x * 9 + i] = u[i];
  }
  __syncthreads();
  if (threadIdx.x == 0) {
    float u[9];
#pragma unroll
    for (int i = 0; i < 9; ++i) u[i] = 3e38f;
    for (int s = 0; s < 32; ++s)
#pragma unroll
      for (int i = 0; i < 9; ++i) ins9(u, l9b[s * 9 + i]);
#pragma unroll
    for (int i = 0; i < 9; ++i) top9[bc * 9 + i] = u[i];
  }
}

// ---------------- K6: pick exact argmax candidate, compute score ----------------
__global__ void score_kernel(const float* __restrict__ top9, const int* __restrict__ cand,
                             float* __restrict__ out) {
  const int b = threadIdx.x;
  if (b >= B_) return;
  float bestv = -3e38f; int bestc = 0, bestp = 1 << 30;
  for (int c = 0; c < NC_; ++c) {
    float v = top9[(b * NC_ + c) * 9 + 0];
    int p = cand[b * NC_ + c];
    if (v > bestv || (v == bestv && p < bestp)) { bestv = v; bestc = c; bestp = p; }
  }
  const float* v9 = &top9[(b * NC_ + bestc) * 9];
  float mx = v9[8];  // sorted ascending
  float sum = 0.f, mxe = 0.f;
  for (int i = 0; i < 9; ++i) {
    float e = expf(v9[i] - mx);
    sum += e;
    if (e > mxe) mxe = e;
  }
  out[b] = (1.f - mxe / sum) * bestv;
}

// ---------------- launch ----------------
extern "C" void kernel_launch(void* const* d_in, const int* in_sizes, int n_in,
                              void* d_out, int out_size, void* d_ws, size_t ws_size,
                              hipStream_t stream) {
  const float* x = (const float*)d_in[0];
  const float* mem = (const float*)d_in[1];
  float* out = (float*)d_out;
  char* ws = (char*)d_ws;

  // ws layout (~44 MB)
  unsigned char* xq    = (unsigned char*)(ws);                  //  9,830,400
  unsigned char* mq    = (unsigned char*)(ws + 9830400);        // 31,064,064
  float* x2            = (float*)(ws + 40894464);               // 25,600
  float* m2            = (float*)(ws + 40920064);               // 80,896
  unsigned* closest_enc= (unsigned*)(ws + 41000960);            // 25,600
  int*   cand          = (int*)  (ws + 41026560);               // 256
  float* ctop          = (float*)(ws + 41026816);               // 2,880,000
  float* top9          = (float*)(ws + 43906816);               // 2,304

  convert_all<<<NPAD2 + MPAD, 256, 0, stream>>>(x, mem, xq, mq, x2, m2, closest_enc);
  gemm_min8<<<MT2 * NT2, 512, 0, stream>>>(xq, mq, m2, closest_enc);
  topcand_kernel<<<B_, 256, 0, stream>>>(closest_enc, x2, cand);
  cand_dist9<<<NBLK, 256, 0, stream>>>(x, mem, x2, m2, cand, ctop);
  merge_top9<<<B_ * NC_, 256, 0, stream>>>(ctop, top9);
  score_kernel<<<1, 64, 0, stream>>>(top9, cand, out);
}

// Round 15
// 442.758 us; speedup vs baseline: 2.7044x; 2.7044x over previous
//
#include <hip/hip_runtime.h>
#include <math.h>

// Problem constants (reference: B,P,D,N,K = 8,784,1536,20000,9)
#define B_    8
#define P_    784
#define M_    6272      // B*P
#define D_    1536
#define N_    20000
#define NC_   8         // candidate patches per image (fp8 ranking noise -> wider net)

// 256x256 fp8 GEMM geometry (BK = 128 fp8 = one MFMA K-step)
#define MPAD  6400      // 25*256
#define NPAD2 20224     // 79*256
#define MT2   25
#define NT2   79
#define KT2   12        // 1536/128 K-tiles

#define NBLK  1250      // cand-dist blocks of 16 rows (1250*16 = 20000 exactly)

using i32x8  = __attribute__((ext_vector_type(8))) int;
using f32x4v = __attribute__((ext_vector_type(4))) float;

#define GLD_LDS16(src, dst)                                            \
  __builtin_amdgcn_global_load_lds(                                    \
      (__attribute__((address_space(1))) const void*)(src),            \
      (__attribute__((address_space(3))) void*)(dst), 16, 0, 0)

// order-preserving float<->uint for atomicMin (all finite values)
__device__ __forceinline__ unsigned fenc(float f) {
  unsigned u = __float_as_uint(f);
  return (u >> 31) ? ~u : (u | 0x80000000u);
}
__device__ __forceinline__ float fdec(unsigned k) {
  return (k >> 31) ? __uint_as_float(k & 0x7FFFFFFFu) : __uint_as_float(~k);
}

// Branchless sorted-ascending top-9 insert, compile-time indices ONLY (rule #20:
// runtime-indexed arrays spill to scratch).
__device__ __forceinline__ void ins9(float* t, float v) {
  float tim1 = t[0];
  t[0] = fminf(t[0], v);
#pragma unroll
  for (int i = 1; i < 9; ++i) {
    float cur = t[i];
    t[i] = fminf(cur, fmaxf(tim1, v));
    tim1 = cur;
  }
}

// ---------------- K1: fused fp32 -> fp8 (HW cvt) + row sum-of-squares + min-buffer init ------
__device__ __forceinline__ void convert_one(const float* __restrict__ src,
                                            unsigned char* __restrict__ dst,
                                            float* __restrict__ sq,
                                            int row, int realrows) {
  const int t = threadIdx.x;
  if (row >= realrows) {
    unsigned* w = (unsigned*)(dst + (size_t)row * D_);
    for (int i = t; i < D_ / 4; i += 256) w[i] = 0u;   // fp8 zero
    if (t == 0) sq[row] = 1e30f;
    return;
  }
  const float4* r4 = (const float4*)(src + (size_t)row * D_);
  unsigned* w = (unsigned*)(dst + (size_t)row * D_);
  float s = 0.f;
  for (int i = t; i < D_ / 4; i += 256) {
    float4 v = r4[i];
    s += v.x * v.x + v.y * v.y + v.z * v.z + v.w * v.w;
    int pk = __builtin_amdgcn_cvt_pk_fp8_f32(v.x, v.y, 0, false);   // low 16 bits
    pk     = __builtin_amdgcn_cvt_pk_fp8_f32(v.z, v.w, pk, true);   // high 16 bits
    w[i] = (unsigned)pk;
  }
#pragma unroll
  for (int m = 32; m >= 1; m >>= 1) s += __shfl_xor(s, m);
  __shared__ float ws4[4];
  if ((t & 63) == 0) ws4[t >> 6] = s;
  __syncthreads();
  if (t == 0) sq[row] = ws4[0] + ws4[1] + ws4[2] + ws4[3];
}

__global__ void convert_all(const float* __restrict__ x, const float* __restrict__ mem,
                            unsigned char* __restrict__ xq, unsigned char* __restrict__ mq,
                            float* __restrict__ x2, float* __restrict__ m2,
                            unsigned* __restrict__ closest_enc) {
  const int blk = blockIdx.x;
  if (blk < MPAD / 256)   // fold the min-buffer init (per-call reinit; replay-safe)
    closest_enc[blk * 256 + threadIdx.x] = 0xFFFFFFFFu;
  if (blk < NPAD2) convert_one(mem, mq, m2, blk, N_);
  else convert_one(x, xq, x2, blk - NPAD2, M_);
}

// ---------------- K2: 256x256 fp8 MX-MFMA GEMM (identity scales), epilogue -> atomicMin -------
// Round-8/13 verified structure (best measured: 223us, MfmaUtil 38%). 2 phases/K-tile, T2
// swizzle (byte^=((row&7)<<4), inverse-swizzled source), T4 counted vmcnt, T5 setprio.
// [Round 14's B-in-registers variant spilled (WRITE 2.1GB scratch) and thrashed L2 -> reverted.]
__global__ __launch_bounds__(512, 2) void gemm_min8(
    const unsigned char* __restrict__ xq, const unsigned char* __restrict__ mq,
    const float* __restrict__ m2, unsigned* __restrict__ closest_enc) {
  __shared__ __attribute__((aligned(16))) char ldsFlat[131072];
  __shared__ float ldsMin[4][256];

  // --- block swizzle: bijective XCD chunking + 5-mTile supertiles ---
  const int NWG = MT2 * NT2;              // 1975
  const int bid = blockIdx.x;
  const int q = NWG >> 3, r = NWG & 7;    // 246, 7
  const int xcd = bid & 7, loc = bid >> 3;
  const int wg = (xcd < r ? xcd * (q + 1) : r * (q + 1) + (xcd - r) * q) + loc;
  const int s = wg / (5 * NT2);
  const int r2 = wg - s * (5 * NT2);
  const int mT = s * 5 + (r2 % 5);
  const int nT = r2 / 5;

  const int tid = threadIdx.x;
  const int lane = tid & 63, wid = tid >> 6;
  const int wm = wid >> 2, wn = wid & 3;      // 2 x 4 wave grid
  const int g = lane >> 4, r16 = lane & 15;
  const int mBase = mT * 256, nBase = nT * 256;

  const int stRow = wid * 8 + (lane >> 3);
  const int stA = mBase + stRow;
  const int stB = nBase + stRow;
  const int cswz16 = ((lane & 7) ^ ((lane >> 3) & 7)) * 16;  // inverse-swizzled byte col

  // reader: row byte-offset row*128; k-chunk (g*32) swizzled by ((r16&7)<<4)
  const int csl = (g * 32) ^ ((r16 & 7) << 4);
  const int csh = csl ^ 16;                       // (g*32+16)^swz, since bit4 of g*32 == 0
  const int rdA = wm * 16384 + r16 * 128;         // + mf*2048 (+ buf*32768)
  const int rdB = wn * 8192 + r16 * 128;          // + nf*2048 (+ 65536 + buf*32768)

#define STAGE(matsel, srcp, rowb, bufb, h, ktv) do {                        \
    char* dst_ = ldsFlat + (matsel) * 65536 + (bufb) * 32768 +              \
                 (h) * 16384 + wid * 1024;                                  \
    const unsigned char* s_ =                                               \
        (srcp) + (size_t)((rowb) + (h) * 128) * 1536 + (ktv) * 128 + cswz16;\
    GLD_LDS16(s_, dst_);                                                    \
    GLD_LDS16(s_ + 64 * 1536, dst_ + 8192);                                 \
  } while (0)

#define LDFRAG(base, off) ({                                                \
    int4 lo_ = *(const int4*)((base) + (off) + csl);                        \
    int4 hi_ = *(const int4*)((base) + (off) + csh);                        \
    i32x8{lo_.x, lo_.y, lo_.z, lo_.w, hi_.x, hi_.y, hi_.z, hi_.w}; })

#define MFMA8(a, b, c) __builtin_amdgcn_mfma_scale_f32_16x16x128_f8f6f4(    \
    (a), (b), (c), 0, 0, 0, 0x7F7F7F7F, 0, 0x7F7F7F7F)

  f32x4v acc[8][4];
#pragma unroll
  for (int i = 0; i < 8; ++i)
#pragma unroll
    for (int j = 0; j < 4; ++j) acc[i][j] = f32x4v{0.f, 0.f, 0.f, 0.f};

  // ---- prologue: B(0), A(0), B(1); wait first 8 of 12 loads ----
  STAGE(1, mq, stB, 0, 0, 0);
  STAGE(1, mq, stB, 0, 1, 0);
  STAGE(0, xq, stA, 0, 0, 0);
  STAGE(0, xq, stA, 0, 1, 0);
  STAGE(1, mq, stB, 1, 0, 1);
  STAGE(1, mq, stB, 1, 1, 1);
  asm volatile("s_waitcnt vmcnt(4)");
  __builtin_amdgcn_s_barrier();
  __builtin_amdgcn_sched_barrier(0);

#pragma unroll 1
  for (int kt = 0; kt < KT2; ++kt) {
    const int bufc = kt & 1;
    const char* Ab = ldsFlat + bufc * 32768;
    const char* Bb = ldsFlat + 65536 + bufc * 32768;
    const bool stgA = (kt + 1) < KT2;
    const bool stgB = (kt + 2) < KT2;
    i32x8 bf[4], af[4];

    // ---- Phase A: read all B + A(mf0-3); stage A(kt+1); 16 MFMA ----
#pragma unroll
    for (int nf = 0; nf < 4; ++nf) bf[nf] = LDFRAG(Bb, rdB + nf * 2048);
#pragma unroll
    for (int mf = 0; mf < 4; ++mf) af[mf] = LDFRAG(Ab, rdA + mf * 2048);
    if (stgA) {
      STAGE(0, xq, stA, bufc ^ 1, 0, kt + 1);
      STAGE(0, xq, stA, bufc ^ 1, 1, kt + 1);
    }
    __builtin_amdgcn_s_barrier();
    asm volatile("s_waitcnt lgkmcnt(0)");
    __builtin_amdgcn_s_setprio(1);
#pragma unroll
    for (int mf = 0; mf < 4; ++mf)
#pragma unroll
      for (int nf = 0; nf < 4; ++nf)
        acc[mf][nf] = MFMA8(af[mf], bf[nf], acc[mf][nf]);
    __builtin_amdgcn_s_setprio(0);
    __builtin_amdgcn_s_barrier();

    // ---- Phase B: read A(mf4-7); stage B(kt+2) -> same buf (B fully read); 16 MFMA ----
#pragma unroll
    for (int mf = 0; mf < 4; ++mf) af[mf] = LDFRAG(Ab, rdA + (mf + 4) * 2048);
    if (stgB) {
      STAGE(1, mq, stB, bufc, 0, kt + 2);
      STAGE(1, mq, stB, bufc, 1, kt + 2);
    }
    __builtin_amdgcn_s_barrier();
    asm volatile("s_waitcnt lgkmcnt(0)");
    __builtin_amdgcn_s_setprio(1);
#pragma unroll
    for (int mf = 0; mf < 4; ++mf)
#pragma unroll
      for (int nf = 0; nf < 4; ++nf)
        acc[mf + 4][nf] = MFMA8(af[mf], bf[nf], acc[mf + 4][nf]);
    __builtin_amdgcn_s_setprio(0);
    if (kt >= KT2 - 2) {  // tail: stages skipped, counts shift -> full drain
      asm volatile("s_waitcnt vmcnt(0)");
    } else {              // steady: allow B(kt+2)'s 4 loads outstanding
      asm volatile("s_waitcnt vmcnt(4)");
    }
    __builtin_amdgcn_s_barrier();
    __builtin_amdgcn_sched_barrier(0);
  }
#undef STAGE
#undef LDFRAG
#undef MFMA8

  // ---- epilogue: per-row min over this tile's 256 cols -> global atomicMin ----
  // C/D layout: col = nBase + wn*64 + nf*16 + (lane&15), row = wm*128 + mf*16 + (lane>>4)*4 + i
  float m2v[4];
#pragma unroll
  for (int nf = 0; nf < 4; ++nf) m2v[nf] = m2[nBase + wn * 64 + nf * 16 + r16];
#pragma unroll
  for (int mf = 0; mf < 8; ++mf) {
    float mn[4];
#pragma unroll
    for (int i = 0; i < 4; ++i) {
      float v = m2v[0] - 2.f * acc[mf][0][i];
      v = fminf(v, m2v[1] - 2.f * acc[mf][1][i]);
      v = fminf(v, m2v[2] - 2.f * acc[mf][2][i]);
      v = fminf(v, m2v[3] - 2.f * acc[mf][3][i]);
      mn[i] = v;
    }
#pragma unroll
    for (int msk = 1; msk < 16; msk <<= 1)
#pragma unroll
      for (int i = 0; i < 4; ++i) mn[i] = fminf(mn[i], __shfl_xor(mn[i], msk));
    if (r16 == 0)
#pragma unroll
      for (int i = 0; i < 4; ++i)
        ldsMin[wn][wm * 128 + mf * 16 + g * 4 + i] = mn[i];
  }
  __syncthreads();
  if (tid < 256) {
    float v = fminf(fminf(ldsMin[0][tid], ldsMin[1][tid]),
                    fminf(ldsMin[2][tid], ldsMin[3][tid]));
    atomicMin(&closest_enc[mBase + tid], fenc(v));
  }
}

// ---------------- K3: per image, closest = x2 + decoded min; wave-parallel top-NC ----------------
__global__ void topcand_kernel(const unsigned* __restrict__ closest_enc,
                               const float* __restrict__ x2,
                               int* __restrict__ cand) {
  const int b = blockIdx.x;
  const int t = threadIdx.x;
  __shared__ float cls[P_];
  for (int p = t; p < P_; p += 256) {
    const int row = b * P_ + p;
    cls[p] = x2[row] + fdec(closest_enc[row]);
  }
  __syncthreads();
  __shared__ float wv[4];
  __shared__ int wi_[4];
  __shared__ int picked[NC_];
  for (int r = 0; r < NC_; ++r) {
    float mv = -3e38f; int mi = 1 << 30;
    for (int p = t; p < P_; p += 256) {
      bool skip = false;
      for (int c = 0; c < r; ++c) skip |= (picked[c] == p);
      float v = cls[p];
      if (!skip && (v > mv || (v == mv && p < mi))) { mv = v; mi = p; }
    }
#pragma unroll
    for (int m = 32; m >= 1; m >>= 1) {
      float ov = __shfl_xor(mv, m); int oi = __shfl_xor(mi, m);
      if (ov > mv || (ov == mv && oi < mi)) { mv = ov; mi = oi; }
    }
    if ((t & 63) == 0) { wv[t >> 6] = mv; wi_[t >> 6] = mi; }
    __syncthreads();
    if (t == 0) {
      float bv = wv[0]; int bi = wi_[0];
      for (int w = 1; w < 4; ++w)
        if (wv[w] > bv || (wv[w] == bv && wi_[w] < bi)) { bv = wv[w]; bi = wi_[w]; }
      picked[r] = bi;
      cand[b * NC_ + r] = bi;
    }
    __syncthreads();
  }
}

// ---------------- K4: exact fp32 distances, ONE pass over memory + per-block top-9 ----------------
// 1250 blocks x 4 waves; each wave owns 4 rows (m4[4][6] = 96 VGPR, spill-free).
__global__ __launch_bounds__(256) void cand_dist9(
    const float* __restrict__ x, const float* __restrict__ mem,
    const float* __restrict__ x2, const float* __restrict__ m2,
    const int* __restrict__ cand, float* __restrict__ ctop) {
  const int wid = threadIdx.x >> 6, lane = threadIdx.x & 63;
  const int blk = blockIdx.x;
  __shared__ float ldsD[B_ * NC_][20];  // [pair][row-in-block], padded (2-way bank alias = free)

  const int rbase = blk * 16 + wid * 4;
  float4 m4[4][6];
  float m2r[4];
#pragma unroll
  for (int k = 0; k < 4; ++k) {
    const float4* mrow = (const float4*)(mem + (size_t)(rbase + k) * D_);
#pragma unroll
    for (int j = 0; j < 6; ++j) m4[k][j] = mrow[j * 64 + lane];
    m2r[k] = m2[rbase + k];
  }
#pragma unroll 2
  for (int bc = 0; bc < B_ * NC_; ++bc) {
    const int b = bc / NC_;
    const int p = cand[bc];
    const float4* xp = (const float4*)(x + ((size_t)b * P_ + p) * D_);
    float s0 = 0.f, s1 = 0.f, s2 = 0.f, s3 = 0.f;
#pragma unroll
    for (int j = 0; j < 6; ++j) {
      float4 a = xp[j * 64 + lane];
      s0 += a.x * m4[0][j].x + a.y * m4[0][j].y + a.z * m4[0][j].z + a.w * m4[0][j].w;
      s1 += a.x * m4[1][j].x + a.y * m4[1][j].y + a.z * m4[1][j].z + a.w * m4[1][j].w;
      s2 += a.x * m4[2][j].x + a.y * m4[2][j].y + a.z * m4[2][j].z + a.w * m4[2][j].w;
      s3 += a.x * m4[3][j].x + a.y * m4[3][j].y + a.z * m4[3][j].z + a.w * m4[3][j].w;
    }
#pragma unroll
    for (int msk = 32; msk >= 1; msk >>= 1) {
      s0 += __shfl_xor(s0, msk); s1 += __shfl_xor(s1, msk);
      s2 += __shfl_xor(s2, msk); s3 += __shfl_xor(s3, msk);
    }
    if (lane == 0) {
      const float xx = x2[b * P_ + p];
      ldsD[bc][wid * 4 + 0] = xx + m2r[0] - 2.f * s0;
      ldsD[bc][wid * 4 + 1] = xx + m2r[1] - 2.f * s1;
      ldsD[bc][wid * 4 + 2] = xx + m2r[2] - 2.f * s2;
      ldsD[bc][wid * 4 + 3] = xx + m2r[3] - 2.f * s3;
    }
  }
  __syncthreads();
  if (lane < 16) {
    const int bc = wid * 16 + lane;
    float t[9];
#pragma unroll
    for (int i = 0; i < 9; ++i) t[i] = 3e38f;
#pragma unroll
    for (int i = 0; i < 16; ++i) ins9(t, ldsD[bc][i]);
    float* o = ctop + ((size_t)bc * NBLK + blk) * 9;
#pragma unroll
    for (int i = 0; i < 9; ++i) o[i] = t[i];
  }
}

// ---------------- K5: merge per-block top-9 partials -> exact top-9 per (image,cand) ----------
__global__ void merge_top9(const float* __restrict__ ctop, float* __restrict__ top9) {
  const int bc = blockIdx.x;  // 0..63
  const float* d = ctop + (size_t)bc * (NBLK * 9);
  float t[9];
#pragma unroll
  for (int i = 0; i < 9; ++i) t[i] = 3e38f;
  for (int n = threadIdx.x; n < NBLK * 9; n += 256) ins9(t, d[n]);
  __shared__ float l9[256 * 9];
  __shared__ float l9b[32 * 9];
#pragma unroll
  for (int i = 0; i < 9; ++i) l9[threadIdx.x * 9 + i] = t[i];
  __syncthreads();
  if (threadIdx.x < 32) {
    float u[9];
#pragma unroll
    for (int i = 0; i < 9; ++i) u[i] = 3e38f;
    for (int s = 0; s < 8; ++s)
#pragma unroll
      for (int i = 0; i < 9; ++i) ins9(u, l9[(threadIdx.x * 8 + s) * 9 + i]);
#pragma unroll
    for (int i = 0; i < 9; ++i) l9b[threadIdx.x * 9 + i] = u[i];
  }
  __syncthreads();
  if (threadIdx.x == 0) {
    float u[9];
#pragma unroll
    for (int i = 0; i < 9; ++i) u[i] = 3e38f;
    for (int s = 0; s < 32; ++s)
#pragma unroll
      for (int i = 0; i < 9; ++i) ins9(u, l9b[s * 9 + i]);
#pragma unroll
    for (int i = 0; i < 9; ++i) top9[bc * 9 + i] = u[i];
  }
}

// ---------------- K6: pick exact argmax candidate, compute score ----------------
__global__ void score_kernel(const float* __restrict__ top9, const int* __restrict__ cand,
                             float* __restrict__ out) {
  const int b = threadIdx.x;
  if (b >= B_) return;
  float bestv = -3e38f; int bestc = 0, bestp = 1 << 30;
  for (int c = 0; c < NC_; ++c) {
    float v = top9[(b * NC_ + c) * 9 + 0];
    int p = cand[b * NC_ + c];
    if (v > bestv || (v == bestv && p < bestp)) { bestv = v; bestc = c; bestp = p; }
  }
  const float* v9 = &top9[(b * NC_ + bestc) * 9];
  float mx = v9[8];  // sorted ascending
  float sum = 0.f, mxe = 0.f;
  for (int i = 0; i < 9; ++i) {
    float e = expf(v9[i] - mx);
    sum += e;
    if (e > mxe) mxe = e;
  }
  out[b] = (1.f - mxe / sum) * bestv;
}

// ---------------- launch ----------------
extern "C" void kernel_launch(void* const* d_in, const int* in_sizes, int n_in,
                              void* d_out, int out_size, void* d_ws, size_t ws_size,
                              hipStream_t stream) {
  const float* x = (const float*)d_in[0];
  const float* mem = (const float*)d_in[1];
  float* out = (float*)d_out;
  char* ws = (char*)d_ws;

  // ws layout (~44 MB)
  unsigned char* xq    = (unsigned char*)(ws);                  //  9,830,400
  unsigned char* mq    = (unsigned char*)(ws + 9830400);        // 31,064,064
  float* x2            = (float*)(ws + 40894464);               // 25,600
  float* m2            = (float*)(ws + 40920064);               // 80,896
  unsigned* closest_enc= (unsigned*)(ws + 41000960);            // 25,600
  int*   cand          = (int*)  (ws + 41026560);               // 256
  float* ctop          = (float*)(ws + 41026816);               // 2,880,000
  float* top9          = (float*)(ws + 43906816);               // 2,304

  convert_all<<<NPAD2 + MPAD, 256, 0, stream>>>(x, mem, xq, mq, x2, m2, closest_enc);
  gemm_min8<<<MT2 * NT2, 512, 0, stream>>>(xq, mq, m2, closest_enc);
  topcand_kernel<<<B_, 256, 0, stream>>>(closest_enc, x2, cand);
  cand_dist9<<<NBLK, 256, 0, stream>>>(x, mem, x2, m2, cand, ctop);
  merge_top9<<<B_ * NC_, 256, 0, stream>>>(ctop, top9);
  score_kernel<<<1, 64, 0, stream>>>(top9, cand, out);
}